// Round 11
// baseline (376.052 us; speedup 1.0000x reference)
//
#include <hip/hip_runtime.h>
#include <stdint.h>

#define B_ 128
#define T_ 1000
#define H_ 512
#define PH 8          // steps per phase
#define NPHASE 125    // T_/PH

typedef float vfloat4 __attribute__((ext_vector_type(4)));

// DPP-based add of a lane-shifted copy. row_shr:N = 0x110|N, row_bcast:15/31 = 0x142/0x143.
template <int CTRL>
__device__ __forceinline__ float dpp_add(float x) {
    int moved = __builtin_amdgcn_update_dpp(0, __float_as_int(x), CTRL, 0xf, 0xf, true);
    return x + __int_as_float(moved);
}

// Wave64 sum of 2 values simultaneously. Totals valid in lane 63.
__device__ __forceinline__ void wave_reduce2(float& p0, float& p1) {
    p0 = dpp_add<0x111>(p0); p1 = dpp_add<0x111>(p1);
    p0 = dpp_add<0x112>(p0); p1 = dpp_add<0x112>(p1);
    p0 = dpp_add<0x114>(p0); p1 = dpp_add<0x114>(p1);
    p0 = dpp_add<0x118>(p0); p1 = dpp_add<0x118>(p1);
    p0 = dpp_add<0x142>(p0); p1 = dpp_add<0x142>(p1);
    p0 = dpp_add<0x143>(p0); p1 = dpp_add<0x143>(p1);
}

// Wave64 sum of 1 value. Valid in lane 63.
__device__ __forceinline__ float wave_reduce1(float p) {
    p = dpp_add<0x111>(p); p = dpp_add<0x112>(p); p = dpp_add<0x114>(p);
    p = dpp_add<0x118>(p); p = dpp_add<0x142>(p); p = dpp_add<0x143>(p);
    return p;
}

// tanh(x) = 1 - 2/(e^{2x}+1) via hardware exp2 + rcp (used off-loop only).
__device__ __forceinline__ float fast_tanh(float x) {
    float E = __builtin_amdgcn_exp2f(x * 2.885390081777927f);
    float r = __builtin_amdgcn_rcpf(E + 1.0f);
    return __builtin_fmaf(-2.0f, r, 1.0f);
}

#define C2_ 2.885390081777927f   // 2*log2(e)
#define C6_ 0.16666666666666666f

__global__ __launch_bounds__(128, 1) void lowrank_rnn_kernel(
    const float* __restrict__ input,   // (B,T,3)
    const float* __restrict__ noise,   // (B,T,H)
    const float* __restrict__ wi,      // (3,H)
    const float* __restrict__ si,      // (3,)
    const float* __restrict__ m,       // (H,2)
    const float* __restrict__ n,       // (H,2)
    const float* __restrict__ wo,      // (H,1)
    const float* __restrict__ so,      // (1,)
    const float* __restrict__ h0,      // (H,)
    float* __restrict__ out)           // [output (B,T,1) | traj (B,T+1,H)]
{
    const int b    = blockIdx.x;   // one batch element per block (2 waves)
    const int tid  = threadIdx.x;
    const int wid  = tid >> 6;     // 0 = consumer (serial chain), 1 = producer
    const int lane = tid & 63;
    const int j0   = lane * 8;     // hidden units j0..j0+7 owned by this lane

    // Rings: [half][row-in-phase][plane][lane] — 16B/lane stride, conflict-free.
    __shared__ __align__(16) vfloat4 ub[2][PH][2][64];   // 32 KB: u = 0.05z + x·wS
    __shared__ __align__(16) vfloat4 rb[2][PH][2][64];   // 32 KB: r = tanh(h_t)
    __shared__ __align__(16) vfloat4 hb[2][PH][2][64];   // 32 KB: h_{t+1}
    __shared__ __align__(16) vfloat4 rfin[2][64];        //  2 KB: final r
    __shared__ float os[T_ + 1];                         //  4 KB
    __shared__ int   flags[2];                           // [0]=vprod, [1]=vcons

    if (tid == 0) { flags[0] = 0; flags[1] = 0; }
    __syncthreads();   // only full barrier in the kernel
    volatile int* vprod = &flags[0];
    volatile int* vcons = &flags[1];

    if (wid == 1) {
        // ========== PRODUCER: z loads, u precompute, os dot, traj stores ==========
        float wS0[8], wS1[8], wS2[8], wof[8];
        {
            const float so0 = so[0];
            #pragma unroll
            for (int i = 0; i < 3; ++i) {
                float s = 0.2f * si[i];
                float* dst = (i == 0) ? wS0 : (i == 1) ? wS1 : wS2;
                #pragma unroll
                for (int q = 0; q < 2; ++q) {
                    vfloat4 vw = *(const vfloat4*)(wi + i * H_ + j0 + 4 * q);
                    dst[4*q] = vw.x * s; dst[4*q+1] = vw.y * s;
                    dst[4*q+2] = vw.z * s; dst[4*q+3] = vw.w * s;
                }
            }
            #pragma unroll
            for (int q = 0; q < 2; ++q) {
                vfloat4 vw = *(const vfloat4*)(wo + j0 + 4 * q);
                wof[4*q] = vw.x * so0; wof[4*q+1] = vw.y * so0;
                wof[4*q+2] = vw.z * so0; wof[4*q+3] = vw.w * so0;
            }
        }
        const float* zb = noise + (size_t)b * T_ * H_ + j0;
        const float* xb = input + (size_t)b * T_ * 3;    // wave-uniform
        float* trajBase = out + (size_t)B_ * T_ + (size_t)b * (T_ + 1) * H_;

        {   // trajectories[:,0,:] = h0 (one-time)
            vfloat4 a = *(const vfloat4*)(h0 + j0);
            vfloat4 c = *(const vfloat4*)(h0 + j0 + 4);
            *(vfloat4*)(trajBase + j0)     = a;
            *(vfloat4*)(trajBase + j0 + 4) = c;
        }

        // os dot + traj stores for a finished phase pp (requires vcons >= pp+1).
        auto emit_phase = [&](int pp) {
            const int hf = pp & 1;
            #pragma unroll
            for (int s = 0; s < PH; ++s) {
                const int t = pp * PH + s;
                vfloat4 rl = rb[hf][s][0][lane];
                vfloat4 rh = rb[hf][s][1][lane];
                float p2 = rl.x * wof[0];
                p2 = __builtin_fmaf(rl.y, wof[1], p2);
                p2 = __builtin_fmaf(rl.z, wof[2], p2);
                p2 = __builtin_fmaf(rl.w, wof[3], p2);
                p2 = __builtin_fmaf(rh.x, wof[4], p2);
                p2 = __builtin_fmaf(rh.y, wof[5], p2);
                p2 = __builtin_fmaf(rh.z, wof[6], p2);
                p2 = __builtin_fmaf(rh.w, wof[7], p2);
                p2 = wave_reduce1(p2);
                if (lane == 63) os[t] = p2;      // out[t-1]
                vfloat4 hl = hb[hf][s][0][lane];
                vfloat4 hh = hb[hf][s][1][lane];
                float* tr = trajBase + (size_t)(t + 1) * H_ + j0;
                *(vfloat4*)tr       = hl;
                *(vfloat4*)(tr + 4) = hh;
            }
        };

        for (int q = 0; q < NPHASE; ++q) {
            if (q >= 2) {                        // ring space + phase q-2 finished
                while (*vcons < q - 1) {}
                asm volatile("" ::: "memory");
            }
            // Issue z loads for phase q first; emit_phase below hides their latency.
            vfloat4 zl[PH], zh[PH];
            #pragma unroll
            for (int s = 0; s < PH; ++s) {
                const float* g = zb + (size_t)(q * PH + s) * H_;
                zl[s] = *(const vfloat4*)g;
                zh[s] = *(const vfloat4*)(g + 4);
            }
            if (q >= 2) emit_phase(q - 2);
            const int half = q & 1;
            #pragma unroll
            for (int s = 0; s < PH; ++s) {
                const int t = q * PH + s;
                float x0 = xb[3*t], x1 = xb[3*t+1], x2 = xb[3*t+2];
                float zz[8] = {zl[s].x, zl[s].y, zl[s].z, zl[s].w,
                               zh[s].x, zh[s].y, zh[s].z, zh[s].w};
                float u[8];
                #pragma unroll
                for (int k = 0; k < 8; ++k) {
                    float xw = __builtin_fmaf(x0, wS0[k],
                               __builtin_fmaf(x1, wS1[k], x2 * wS2[k]));
                    u[k] = __builtin_fmaf(zz[k], 0.05f, xw);
                }
                vfloat4 ulo = {u[0], u[1], u[2], u[3]};
                vfloat4 uhi = {u[4], u[5], u[6], u[7]};
                ub[half][s][0][lane] = ulo;
                ub[half][s][1][lane] = uhi;
            }
            asm volatile("s_waitcnt lgkmcnt(0)" ::: "memory");
            if (lane == 0) *vprod = q + 1;   // also certifies os/traj(q-2) done
        }
        // Tail: phases 123, 124, then final output element.
        while (*vcons < NPHASE) {}            // consumer finished phase 124
        asm volatile("" ::: "memory");
        emit_phase(NPHASE - 2);
        emit_phase(NPHASE - 1);
        while (*vcons < NPHASE + 1) {}        // final r available
        asm volatile("" ::: "memory");
        {
            vfloat4 rl = rfin[0][lane], rh = rfin[1][lane];
            float p2 = rl.x * wof[0];
            p2 = __builtin_fmaf(rl.y, wof[1], p2);
            p2 = __builtin_fmaf(rl.z, wof[2], p2);
            p2 = __builtin_fmaf(rl.w, wof[3], p2);
            p2 = __builtin_fmaf(rh.x, wof[4], p2);
            p2 = __builtin_fmaf(rh.y, wof[5], p2);
            p2 = __builtin_fmaf(rh.z, wof[6], p2);
            p2 = __builtin_fmaf(rh.w, wof[7], p2);
            p2 = wave_reduce1(p2);
            if (lane == 63) os[T_] = p2;
        }
        asm volatile("s_waitcnt lgkmcnt(0)" ::: "memory");
        float* outp = out + (size_t)b * T_;
        for (int idx = lane; idx < T_; idx += 64)
            outp[idx] = os[idx + 1];
    } else {
        // ========== CONSUMER: serial chain with exp-factorized tanh ==========
        // Invariant entering each step t:
        //   h[]   = h_t
        //   R0[]  = 1/(1+exp(2*base_{t-1}))     (base_{-1} := h_0)
        //   S0[]  = 1 - R0[]
        //   a0T,a1T = 2*a_{t-1}                 (a_{-1} := 0)
        // Then r_t = 1 - 2*R0*q, q ~ 1/(1+S0*(e^v-1)), v = a0T*m0S + a1T*m1S.
        float h[8], n0v[8], n1v[8], m0S[8], m1S[8], R0[8], S0[8];
        {
            const float* nb = n + 2 * j0;
            const float* mb = m + 2 * j0;
            #pragma unroll
            for (int q = 0; q < 4; ++q) {
                vfloat4 vn = *(const vfloat4*)(nb + 4 * q);
                n0v[2*q] = vn.x; n1v[2*q] = vn.y; n0v[2*q+1] = vn.z; n1v[2*q+1] = vn.w;
                vfloat4 vm = *(const vfloat4*)(mb + 4 * q);
                m0S[2*q] = 0.2f * vm.x;   m1S[2*q] = 0.2f * vm.y;
                m0S[2*q+1] = 0.2f * vm.z; m1S[2*q+1] = 0.2f * vm.w;
            }
            #pragma unroll
            for (int q = 0; q < 2; ++q) {
                vfloat4 vh = *(const vfloat4*)(h0 + j0 + 4 * q);
                h[4*q] = vh.x; h[4*q+1] = vh.y; h[4*q+2] = vh.z; h[4*q+3] = vh.w;
            }
            #pragma unroll
            for (int k = 0; k < 8; ++k) {
                float eb = __builtin_amdgcn_exp2f(h[k] * C2_);
                float r0 = __builtin_amdgcn_rcpf(eb + 1.0f);
                R0[k] = r0; S0[k] = 1.0f - r0;
            }
        }
        float a0T = 0.0f, a1T = 0.0f;

        for (int p = 0; p < NPHASE; ++p) {
            while (*vprod < p + 1) {}        // u ready AND ring slot p&1 free
            asm volatile("" ::: "memory");
            const int half = p & 1;
            vfloat4 cul = ub[half][0][0][lane];
            vfloat4 cuh = ub[half][0][1][lane];
            #pragma unroll
            for (int s = 0; s < PH; ++s) {
                vfloat4 nul, nuh;
                if (s < PH - 1) {            // prefetch next step's u
                    nul = ub[half][s+1][0][lane];
                    nuh = ub[half][s+1][1][lane];
                }
                // ---- on-chain: r_t from (R0,S0,a0T,a1T) — FMA-only ----
                float r[8];
                #pragma unroll
                for (int k = 0; k < 8; ++k) {
                    float v  = __builtin_fmaf(a0T, m0S[k], a1T * m1S[k]);
                    float t1 = __builtin_fmaf(v, C6_, 0.5f);
                    float t2 = __builtin_fmaf(v, t1, 1.0f);
                    float em = v * t2;                       // e^v - 1 (3rd order)
                    float g  = S0[k] * em;
                    float w1 = 1.0f - g;
                    float w2 = __builtin_fmaf(-g, w1, 1.0f);
                    float q  = __builtin_fmaf(-g, w2, 1.0f); // 1/(1+g) (3rd order)
                    float qq = q + q;
                    r[k] = __builtin_fmaf(-R0[k], qq, 1.0f); // 1 - 2*R0*q
                }
                // ---- dots as trees (short chain, p0/p1 ILP) ----
                float u0[8], u1[8];
                #pragma unroll
                for (int k = 0; k < 8; ++k) { u0[k] = r[k] * n0v[k]; u1[k] = r[k] * n1v[k]; }
                float p0 = ((u0[0]+u0[1]) + (u0[2]+u0[3])) + ((u0[4]+u0[5]) + (u0[6]+u0[7]));
                float p1 = ((u1[0]+u1[1]) + (u1[2]+u1[3])) + ((u1[4]+u1[5]) + (u1[6]+u1[7]));

                // ---- off-chain: base_t, exp/rcp pipeline for step t+1 ----
                float uu[8] = {cul.x, cul.y, cul.z, cul.w, cuh.x, cuh.y, cuh.z, cuh.w};
                float base[8], R0n[8], S0n[8];
                #pragma unroll
                for (int k = 0; k < 8; ++k)
                    base[k] = __builtin_fmaf(h[k], 0.8f, uu[k]);
                #pragma unroll
                for (int k = 0; k < 8; ++k) {
                    float eb = __builtin_amdgcn_exp2f(base[k] * C2_);
                    float r0 = __builtin_amdgcn_rcpf(eb + 1.0f);
                    R0n[k] = r0; S0n[k] = 1.0f - r0;
                }

                wave_reduce2(p0, p1);
                float a0 = __int_as_float(__builtin_amdgcn_readlane(__float_as_int(p0), 63));
                float a1 = __int_as_float(__builtin_amdgcn_readlane(__float_as_int(p1), 63));

                #pragma unroll
                for (int k = 0; k < 8; ++k)
                    h[k] = __builtin_fmaf(a0, m0S[k], __builtin_fmaf(a1, m1S[k], base[k]));
                a0T = a0 + a0; a1T = a1 + a1;
                #pragma unroll
                for (int k = 0; k < 8; ++k) { R0[k] = R0n[k]; S0[k] = S0n[k]; }

                // Ship r (for os) and h (for traj) to the producer.
                vfloat4 rlo = {r[0], r[1], r[2], r[3]};
                vfloat4 rhi = {r[4], r[5], r[6], r[7]};
                rb[half][s][0][lane] = rlo;
                rb[half][s][1][lane] = rhi;
                vfloat4 hlo = {h[0], h[1], h[2], h[3]};
                vfloat4 hhi = {h[4], h[5], h[6], h[7]};
                hb[half][s][0][lane] = hlo;
                hb[half][s][1][lane] = hhi;

                cul = nul; cuh = nuh;
            }
            asm volatile("s_waitcnt lgkmcnt(0)" ::: "memory");  // rings visible
            if (lane == 0) *vcons = p + 1;
        }
        // Final r = tanh(h_T) for out[T-1] (one-time: direct tanh is fine).
        while (*vprod < NPHASE) {}           // producer done reading slot
        asm volatile("" ::: "memory");
        float r[8];
        #pragma unroll
        for (int k = 0; k < 8; ++k) r[k] = fast_tanh(h[k]);
        vfloat4 rlo = {r[0], r[1], r[2], r[3]};
        vfloat4 rhi = {r[4], r[5], r[6], r[7]};
        rfin[0][lane] = rlo;
        rfin[1][lane] = rhi;
        asm volatile("s_waitcnt lgkmcnt(0)" ::: "memory");
        if (lane == 0) *vcons = NPHASE + 1;
    }
}

extern "C" void kernel_launch(void* const* d_in, const int* in_sizes, int n_in,
                              void* d_out, int out_size, void* d_ws, size_t ws_size,
                              hipStream_t stream) {
    const float* input = (const float*)d_in[0];
    const float* noise = (const float*)d_in[1];
    const float* wi    = (const float*)d_in[2];
    const float* si    = (const float*)d_in[3];
    const float* m     = (const float*)d_in[4];
    const float* n     = (const float*)d_in[5];
    const float* wo    = (const float*)d_in[6];
    const float* so    = (const float*)d_in[7];
    const float* h0    = (const float*)d_in[8];
    float* out = (float*)d_out;

    hipLaunchKernelGGL(lowrank_rnn_kernel, dim3(B_), dim3(128), 0, stream,
                       input, noise, wi, si, m, n, wo, so, h0, out);
}

// Round 12
// 300.308 us; speedup vs baseline: 1.2522x; 1.2522x over previous
//
#include <hip/hip_runtime.h>
#include <stdint.h>

#define B_ 128
#define T_ 1000
#define H_ 512
#define PH 8          // steps per phase
#define NPHASE 125    // T_/PH

typedef float vfloat4 __attribute__((ext_vector_type(4)));
typedef float vfloat2 __attribute__((ext_vector_type(2)));

// DPP-based add of a lane-shifted copy. row_shr:N = 0x110|N, row_bcast:15/31 = 0x142/0x143.
template <int CTRL>
__device__ __forceinline__ float dpp_add(float x) {
    int moved = __builtin_amdgcn_update_dpp(0, __float_as_int(x), CTRL, 0xf, 0xf, true);
    return x + __int_as_float(moved);
}

// Wave64 sum of 2 values simultaneously. Totals valid in lane 63.
__device__ __forceinline__ void wave_reduce2(float& p0, float& p1) {
    p0 = dpp_add<0x111>(p0); p1 = dpp_add<0x111>(p1);
    p0 = dpp_add<0x112>(p0); p1 = dpp_add<0x112>(p1);
    p0 = dpp_add<0x114>(p0); p1 = dpp_add<0x114>(p1);
    p0 = dpp_add<0x118>(p0); p1 = dpp_add<0x118>(p1);
    p0 = dpp_add<0x142>(p0); p1 = dpp_add<0x142>(p1);
    p0 = dpp_add<0x143>(p0); p1 = dpp_add<0x143>(p1);
}

// Wave64 sum of 1 value. Valid in lane 63.
__device__ __forceinline__ float wave_reduce1(float p) {
    p = dpp_add<0x111>(p); p = dpp_add<0x112>(p); p = dpp_add<0x114>(p);
    p = dpp_add<0x118>(p); p = dpp_add<0x142>(p); p = dpp_add<0x143>(p);
    return p;
}

// tanh(x) = 1 - 2/(e^{2x}+1) via hardware exp2 + rcp (off-loop use).
__device__ __forceinline__ float fast_tanh(float x) {
    float E = __builtin_amdgcn_exp2f(x * 2.885390081777927f);
    float r = __builtin_amdgcn_rcpf(E + 1.0f);
    return __builtin_fmaf(-2.0f, r, 1.0f);
}

#define C2_ 2.885390081777927f   // 2*log2(e)

__device__ __forceinline__ vfloat2 bc2(float x) { vfloat2 v = {x, x}; return v; }

__global__ __launch_bounds__(128, 1) void lowrank_rnn_kernel(
    const float* __restrict__ input,   // (B,T,3)
    const float* __restrict__ noise,   // (B,T,H)
    const float* __restrict__ wi,      // (3,H)
    const float* __restrict__ si,      // (3,)
    const float* __restrict__ m,       // (H,2)
    const float* __restrict__ n,       // (H,2)
    const float* __restrict__ wo,      // (H,1)
    const float* __restrict__ so,      // (1,)
    const float* __restrict__ h0,      // (H,)
    float* __restrict__ out)           // [output (B,T,1) | traj (B,T+1,H)]
{
    const int b    = blockIdx.x;   // one batch element per block (2 waves)
    const int tid  = threadIdx.x;
    const int wid  = tid >> 6;     // 0 = consumer (serial chain), 1 = producer
    const int lane = tid & 63;
    const int j0   = lane * 8;     // hidden units j0..j0+7 owned by this lane

    // Rings: [half][row-in-phase][plane][lane] — 16B/lane stride, conflict-free.
    __shared__ __align__(16) vfloat4 ub[2][PH][2][64];   // 32 KB: u = 0.05z + x·wS
    __shared__ __align__(16) vfloat4 rb[2][PH][2][64];   // 32 KB: r = tanh(h_t)
    __shared__ __align__(16) vfloat4 hb[2][PH][2][64];   // 32 KB: h_{t+1}
    __shared__ __align__(16) vfloat4 rfin[2][64];        //  2 KB: final r
    __shared__ float os[T_ + 1];                         //  4 KB
    __shared__ int   flags[2];                           // [0]=vprod, [1]=vcons

    if (tid == 0) { flags[0] = 0; flags[1] = 0; }
    __syncthreads();   // only full barrier in the kernel
    volatile int* vprod = &flags[0];
    volatile int* vcons = &flags[1];

    if (wid == 1) {
        // ========== PRODUCER: z loads, u precompute, os dot, traj stores ==========
        float wS0[8], wS1[8], wS2[8], wof[8];
        {
            const float so0 = so[0];
            #pragma unroll
            for (int i = 0; i < 3; ++i) {
                float s = 0.2f * si[i];
                float* dst = (i == 0) ? wS0 : (i == 1) ? wS1 : wS2;
                #pragma unroll
                for (int q = 0; q < 2; ++q) {
                    vfloat4 vw = *(const vfloat4*)(wi + i * H_ + j0 + 4 * q);
                    dst[4*q] = vw.x * s; dst[4*q+1] = vw.y * s;
                    dst[4*q+2] = vw.z * s; dst[4*q+3] = vw.w * s;
                }
            }
            #pragma unroll
            for (int q = 0; q < 2; ++q) {
                vfloat4 vw = *(const vfloat4*)(wo + j0 + 4 * q);
                wof[4*q] = vw.x * so0; wof[4*q+1] = vw.y * so0;
                wof[4*q+2] = vw.z * so0; wof[4*q+3] = vw.w * so0;
            }
        }
        const float* zb = noise + (size_t)b * T_ * H_ + j0;
        const float* xb = input + (size_t)b * T_ * 3;    // wave-uniform
        float* trajBase = out + (size_t)B_ * T_ + (size_t)b * (T_ + 1) * H_;

        {   // trajectories[:,0,:] = h0 (one-time)
            vfloat4 a = *(const vfloat4*)(h0 + j0);
            vfloat4 c = *(const vfloat4*)(h0 + j0 + 4);
            *(vfloat4*)(trajBase + j0)     = a;
            *(vfloat4*)(trajBase + j0 + 4) = c;
        }

        // os dot + traj stores for a finished phase pp (requires vcons >= pp+1).
        auto emit_phase = [&](int pp) {
            const int hf = pp & 1;
            #pragma unroll
            for (int s = 0; s < PH; ++s) {
                const int t = pp * PH + s;
                vfloat4 rl = rb[hf][s][0][lane];
                vfloat4 rh = rb[hf][s][1][lane];
                float p2 = rl.x * wof[0];
                p2 = __builtin_fmaf(rl.y, wof[1], p2);
                p2 = __builtin_fmaf(rl.z, wof[2], p2);
                p2 = __builtin_fmaf(rl.w, wof[3], p2);
                p2 = __builtin_fmaf(rh.x, wof[4], p2);
                p2 = __builtin_fmaf(rh.y, wof[5], p2);
                p2 = __builtin_fmaf(rh.z, wof[6], p2);
                p2 = __builtin_fmaf(rh.w, wof[7], p2);
                p2 = wave_reduce1(p2);
                if (lane == 63) os[t] = p2;      // out[t-1]
                vfloat4 hl = hb[hf][s][0][lane];
                vfloat4 hh = hb[hf][s][1][lane];
                float* tr = trajBase + (size_t)(t + 1) * H_ + j0;
                *(vfloat4*)tr       = hl;
                *(vfloat4*)(tr + 4) = hh;
            }
        };

        for (int q = 0; q < NPHASE; ++q) {
            if (q >= 2) {                        // ring space + phase q-2 finished
                while (*vcons < q - 1) {}
                asm volatile("" ::: "memory");
            }
            // Issue z loads for phase q first; emit_phase below hides their latency.
            vfloat4 zl[PH], zh[PH];
            #pragma unroll
            for (int s = 0; s < PH; ++s) {
                const float* g = zb + (size_t)(q * PH + s) * H_;
                zl[s] = *(const vfloat4*)g;
                zh[s] = *(const vfloat4*)(g + 4);
            }
            if (q >= 2) emit_phase(q - 2);
            const int half = q & 1;
            #pragma unroll
            for (int s = 0; s < PH; ++s) {
                const int t = q * PH + s;
                float x0 = xb[3*t], x1 = xb[3*t+1], x2 = xb[3*t+2];
                float zz[8] = {zl[s].x, zl[s].y, zl[s].z, zl[s].w,
                               zh[s].x, zh[s].y, zh[s].z, zh[s].w};
                float u[8];
                #pragma unroll
                for (int k = 0; k < 8; ++k) {
                    float xw = __builtin_fmaf(x0, wS0[k],
                               __builtin_fmaf(x1, wS1[k], x2 * wS2[k]));
                    u[k] = __builtin_fmaf(zz[k], 0.05f, xw);
                }
                vfloat4 ulo = {u[0], u[1], u[2], u[3]};
                vfloat4 uhi = {u[4], u[5], u[6], u[7]};
                ub[half][s][0][lane] = ulo;
                ub[half][s][1][lane] = uhi;
            }
            asm volatile("s_waitcnt lgkmcnt(0)" ::: "memory");
            if (lane == 0) *vprod = q + 1;   // also certifies os/traj(q-2) done
        }
        // Tail: phases 123, 124, then final output element.
        while (*vcons < NPHASE) {}            // consumer finished phase 124
        asm volatile("" ::: "memory");
        emit_phase(NPHASE - 2);
        emit_phase(NPHASE - 1);
        while (*vcons < NPHASE + 1) {}        // final r available
        asm volatile("" ::: "memory");
        {
            vfloat4 rl = rfin[0][lane], rh = rfin[1][lane];
            float p2 = rl.x * wof[0];
            p2 = __builtin_fmaf(rl.y, wof[1], p2);
            p2 = __builtin_fmaf(rl.z, wof[2], p2);
            p2 = __builtin_fmaf(rl.w, wof[3], p2);
            p2 = __builtin_fmaf(rh.x, wof[4], p2);
            p2 = __builtin_fmaf(rh.y, wof[5], p2);
            p2 = __builtin_fmaf(rh.z, wof[6], p2);
            p2 = __builtin_fmaf(rh.w, wof[7], p2);
            p2 = wave_reduce1(p2);
            if (lane == 63) os[T_] = p2;
        }
        asm volatile("s_waitcnt lgkmcnt(0)" ::: "memory");
        float* outp = out + (size_t)b * T_;
        for (int idx = lane; idx < T_; idx += 64)
            outp[idx] = os[idx + 1];
    } else {
        // ========== CONSUMER: serial chain, packed 2xf32 (v_pk_*) ==========
        vfloat2 h2[4], n02[4], n12[4], m02[4], m12[4];
        {
            const float* nb = n + 2 * j0;
            const float* mb = m + 2 * j0;
            #pragma unroll
            for (int q = 0; q < 4; ++q) {
                // pair q covers units {2q, 2q+1}
                vfloat4 vn = *(const vfloat4*)(nb + 4 * q);     // n0[2q],n1[2q],n0[2q+1],n1[2q+1]
                vfloat2 a = {vn.x, vn.z}; n02[q] = a;
                vfloat2 c = {vn.y, vn.w}; n12[q] = c;
                vfloat4 vm = *(const vfloat4*)(mb + 4 * q);
                vfloat2 d = {0.2f * vm.x, 0.2f * vm.z}; m02[q] = d;
                vfloat2 e = {0.2f * vm.y, 0.2f * vm.w}; m12[q] = e;
            }
            #pragma unroll
            for (int q = 0; q < 2; ++q) {
                vfloat4 vh = *(const vfloat4*)(h0 + j0 + 4 * q);
                vfloat2 lo = {vh.x, vh.y}, hi = {vh.z, vh.w};
                h2[2*q] = lo; h2[2*q+1] = hi;
            }
        }

        for (int p = 0; p < NPHASE; ++p) {
            while (*vprod < p + 1) {}        // u ready AND ring slot p&1 free
            asm volatile("" ::: "memory");
            const int half = p & 1;
            vfloat4 cul = ub[half][0][0][lane];
            vfloat4 cuh = ub[half][0][1][lane];
            #pragma unroll
            for (int s = 0; s < PH; ++s) {
                vfloat4 nul, nuh;
                if (s < PH - 1) {            // prefetch next step's u
                    nul = ub[half][s+1][0][lane];
                    nuh = ub[half][s+1][1][lane];
                }
                // tanh: packed wrapper ops around scalar exp2/rcp.
                vfloat2 r2[4];
                #pragma unroll
                for (int j = 0; j < 4; ++j) {
                    vfloat2 x2 = h2[j] * C2_;                    // v_pk_mul
                    vfloat2 E  = {__builtin_amdgcn_exp2f(x2.x),
                                  __builtin_amdgcn_exp2f(x2.y)}; // trans x2
                    vfloat2 D  = E + 1.0f;                       // v_pk_add
                    vfloat2 R  = {__builtin_amdgcn_rcpf(D.x),
                                  __builtin_amdgcn_rcpf(D.y)};   // trans x2
                    r2[j] = bc2(-2.0f) * R + 1.0f;               // v_pk_fma
                }
                // dots (pairwise tree, packed)
                vfloat2 A0 = r2[1] * n02[1] + r2[0] * n02[0];
                vfloat2 B0 = r2[3] * n02[3] + r2[2] * n02[2];
                vfloat2 P0 = A0 + B0;
                float p0 = P0.x + P0.y;
                vfloat2 A1 = r2[1] * n12[1] + r2[0] * n12[0];
                vfloat2 B1 = r2[3] * n12[3] + r2[2] * n12[2];
                vfloat2 P1 = A1 + B1;
                float p1 = P1.x + P1.y;

                wave_reduce2(p0, p1);

                // base (packed) — fills issue slots while DPP chain runs.
                vfloat2 u2[4];
                vfloat2 t0 = {cul.x, cul.y}; u2[0] = t0;
                vfloat2 t1 = {cul.z, cul.w}; u2[1] = t1;
                vfloat2 t2 = {cuh.x, cuh.y}; u2[2] = t2;
                vfloat2 t3 = {cuh.z, cuh.w}; u2[3] = t3;
                vfloat2 base2[4];
                #pragma unroll
                for (int j = 0; j < 4; ++j)
                    base2[j] = h2[j] * 0.8f + u2[j];             // v_pk_fma

                float a0 = __int_as_float(__builtin_amdgcn_readlane(__float_as_int(p0), 63));
                float a1 = __int_as_float(__builtin_amdgcn_readlane(__float_as_int(p1), 63));
                vfloat2 a02 = bc2(a0), a12 = bc2(a1);
                #pragma unroll
                for (int j = 0; j < 4; ++j)
                    h2[j] = a02 * m02[j] + (a12 * m12[j] + base2[j]);  // 2x v_pk_fma

                // Ship r (for os) and h (for traj) to the producer.
                vfloat4 rlo = {r2[0].x, r2[0].y, r2[1].x, r2[1].y};
                vfloat4 rhi = {r2[2].x, r2[2].y, r2[3].x, r2[3].y};
                rb[half][s][0][lane] = rlo;
                rb[half][s][1][lane] = rhi;
                vfloat4 hlo = {h2[0].x, h2[0].y, h2[1].x, h2[1].y};
                vfloat4 hhi = {h2[2].x, h2[2].y, h2[3].x, h2[3].y};
                hb[half][s][0][lane] = hlo;
                hb[half][s][1][lane] = hhi;

                cul = nul; cuh = nuh;
            }
            asm volatile("s_waitcnt lgkmcnt(0)" ::: "memory");  // rings visible
            if (lane == 0) *vcons = p + 1;
        }
        // Final r = tanh(h_T) for out[T-1].
        while (*vprod < NPHASE) {}           // producer done reading slot
        asm volatile("" ::: "memory");
        float hfin[8] = {h2[0].x, h2[0].y, h2[1].x, h2[1].y,
                         h2[2].x, h2[2].y, h2[3].x, h2[3].y};
        float r[8];
        #pragma unroll
        for (int k = 0; k < 8; ++k) r[k] = fast_tanh(hfin[k]);
        vfloat4 rlo = {r[0], r[1], r[2], r[3]};
        vfloat4 rhi = {r[4], r[5], r[6], r[7]};
        rfin[0][lane] = rlo;
        rfin[1][lane] = rhi;
        asm volatile("s_waitcnt lgkmcnt(0)" ::: "memory");
        if (lane == 0) *vcons = NPHASE + 1;
    }
}

extern "C" void kernel_launch(void* const* d_in, const int* in_sizes, int n_in,
                              void* d_out, int out_size, void* d_ws, size_t ws_size,
                              hipStream_t stream) {
    const float* input = (const float*)d_in[0];
    const float* noise = (const float*)d_in[1];
    const float* wi    = (const float*)d_in[2];
    const float* si    = (const float*)d_in[3];
    const float* m     = (const float*)d_in[4];
    const float* n     = (const float*)d_in[5];
    const float* wo    = (const float*)d_in[6];
    const float* so    = (const float*)d_in[7];
    const float* h0    = (const float*)d_in[8];
    float* out = (float*)d_out;

    hipLaunchKernelGGL(lowrank_rnn_kernel, dim3(B_), dim3(128), 0, stream,
                       input, noise, wi, si, m, n, wo, so, h0, out);
}

// Round 14
// 294.536 us; speedup vs baseline: 1.2768x; 1.0196x over previous
//
#include <hip/hip_runtime.h>
#include <stdint.h>

#define B_ 128
#define T_ 1000
#define H_ 512
#define PH 8          // steps per phase
#define NPHASE 125    // T_/PH

typedef float vfloat4 __attribute__((ext_vector_type(4)));
typedef float vfloat2 __attribute__((ext_vector_type(2)));

// DPP-based add of a lane-shifted copy. row_shr:N = 0x110|N, row_bcast:15/31 = 0x142/0x143.
template <int CTRL>
__device__ __forceinline__ float dpp_add(float x) {
    int moved = __builtin_amdgcn_update_dpp(0, __float_as_int(x), CTRL, 0xf, 0xf, true);
    return x + __int_as_float(moved);
}

// Wave64 sum of 2 values simultaneously. Totals valid in lane 63.
__device__ __forceinline__ void wave_reduce2(float& p0, float& p1) {
    p0 = dpp_add<0x111>(p0); p1 = dpp_add<0x111>(p1);
    p0 = dpp_add<0x112>(p0); p1 = dpp_add<0x112>(p1);
    p0 = dpp_add<0x114>(p0); p1 = dpp_add<0x114>(p1);
    p0 = dpp_add<0x118>(p0); p1 = dpp_add<0x118>(p1);
    p0 = dpp_add<0x142>(p0); p1 = dpp_add<0x142>(p1);
    p0 = dpp_add<0x143>(p0); p1 = dpp_add<0x143>(p1);
}

// Wave64 sum of 1 value. Valid in lane 63.
__device__ __forceinline__ float wave_reduce1(float p) {
    p = dpp_add<0x111>(p); p = dpp_add<0x112>(p); p = dpp_add<0x114>(p);
    p = dpp_add<0x118>(p); p = dpp_add<0x142>(p); p = dpp_add<0x143>(p);
    return p;
}

// tanh(x) = 1 - 2/(e^{2x}+1) via hardware exp2 + rcp (off-chain / one-time use).
__device__ __forceinline__ float fast_tanh(float x) {
    float E = __builtin_amdgcn_exp2f(x * 2.885390081777927f);
    float r = __builtin_amdgcn_rcpf(E + 1.0f);
    return __builtin_fmaf(-2.0f, r, 1.0f);
}

#define C2_ 2.885390081777927f   // 2*log2(e)

__device__ __forceinline__ vfloat2 bc2(float x) { vfloat2 v = {x, x}; return v; }

__global__ __launch_bounds__(128, 1) void lowrank_rnn_kernel(
    const float* __restrict__ input,   // (B,T,3)
    const float* __restrict__ noise,   // (B,T,H)
    const float* __restrict__ wi,      // (3,H)
    const float* __restrict__ si,      // (3,)
    const float* __restrict__ m,       // (H,2)
    const float* __restrict__ n,       // (H,2)
    const float* __restrict__ wo,      // (H,1)
    const float* __restrict__ so,      // (1,)
    const float* __restrict__ h0,      // (H,)
    float* __restrict__ out)           // [output (B,T,1) | traj (B,T+1,H)]
{
    const int b    = blockIdx.x;   // one batch element per block (2 waves)
    const int tid  = threadIdx.x;
    const int wid  = tid >> 6;     // 0 = consumer (serial chain), 1 = producer
    const int lane = tid & 63;
    const int j0   = lane * 8;     // hidden units j0..j0+7 owned by this lane

    // Rings: [half][row-in-phase][plane][lane] — 16B/lane stride, conflict-free.
    __shared__ __align__(16) vfloat4 ub[2][PH][2][64];   // 32 KB: u = 0.05z + x·wS
    __shared__ __align__(16) vfloat4 rb[2][PH][2][64];   // 32 KB: r = tanh(h_t)
    __shared__ __align__(16) vfloat4 hb[2][PH][2][64];   // 32 KB: h_t
    __shared__ __align__(16) vfloat4 rfin[2][64];        //  2 KB: final r
    __shared__ __align__(16) vfloat4 hfin[2][64];        //  2 KB: final h_T
    __shared__ float os[T_ + 1];                         //  4 KB
    __shared__ int   flags[2];                           // [0]=vprod, [1]=vcons

    if (tid == 0) { flags[0] = 0; flags[1] = 0; }
    __syncthreads();   // only full barrier in the kernel
    volatile int* vprod = &flags[0];
    volatile int* vcons = &flags[1];

    if (wid == 1) {
        // ========== PRODUCER: z loads, u precompute, os dot, traj stores ==========
        float wS0[8], wS1[8], wS2[8], wof[8];
        {
            const float so0 = so[0];
            #pragma unroll
            for (int i = 0; i < 3; ++i) {
                float s = 0.2f * si[i];
                float* dst = (i == 0) ? wS0 : (i == 1) ? wS1 : wS2;
                #pragma unroll
                for (int q = 0; q < 2; ++q) {
                    vfloat4 vw = *(const vfloat4*)(wi + i * H_ + j0 + 4 * q);
                    dst[4*q] = vw.x * s; dst[4*q+1] = vw.y * s;
                    dst[4*q+2] = vw.z * s; dst[4*q+3] = vw.w * s;
                }
            }
            #pragma unroll
            for (int q = 0; q < 2; ++q) {
                vfloat4 vw = *(const vfloat4*)(wo + j0 + 4 * q);
                wof[4*q] = vw.x * so0; wof[4*q+1] = vw.y * so0;
                wof[4*q+2] = vw.z * so0; wof[4*q+3] = vw.w * so0;
            }
        }
        const float* zb = noise + (size_t)b * T_ * H_ + j0;
        const float* xb = input + (size_t)b * T_ * 3;    // wave-uniform
        float* trajBase = out + (size_t)B_ * T_ + (size_t)b * (T_ + 1) * H_;

        {   // trajectories[:,0,:] = h0 (one-time)
            vfloat4 a = *(const vfloat4*)(h0 + j0);
            vfloat4 c = *(const vfloat4*)(h0 + j0 + 4);
            *(vfloat4*)(trajBase + j0)     = a;
            *(vfloat4*)(trajBase + j0 + 4) = c;
        }

        // os dot + traj stores for a finished phase pp (requires vcons >= pp+1).
        // hb[hf][s] holds h_t for t = pp*PH+s  ->  traj row t.
        auto emit_phase = [&](int pp) {
            const int hf = pp & 1;
            #pragma unroll
            for (int s = 0; s < PH; ++s) {
                const int t = pp * PH + s;
                vfloat4 rl = rb[hf][s][0][lane];
                vfloat4 rh = rb[hf][s][1][lane];
                float p2 = rl.x * wof[0];
                p2 = __builtin_fmaf(rl.y, wof[1], p2);
                p2 = __builtin_fmaf(rl.z, wof[2], p2);
                p2 = __builtin_fmaf(rl.w, wof[3], p2);
                p2 = __builtin_fmaf(rh.x, wof[4], p2);
                p2 = __builtin_fmaf(rh.y, wof[5], p2);
                p2 = __builtin_fmaf(rh.z, wof[6], p2);
                p2 = __builtin_fmaf(rh.w, wof[7], p2);
                p2 = wave_reduce1(p2);
                if (lane == 63) os[t] = p2;      // out[t-1] = tanh(h_t)·wo
                vfloat4 hl = hb[hf][s][0][lane];
                vfloat4 hh = hb[hf][s][1][lane];
                float* tr = trajBase + (size_t)t * H_ + j0;   // row t = h_t
                *(vfloat4*)tr       = hl;
                *(vfloat4*)(tr + 4) = hh;
            }
        };

        for (int q = 0; q < NPHASE; ++q) {
            if (q >= 2) {                        // ring space + phase q-2 finished
                while (*vcons < q - 1) {}
                asm volatile("" ::: "memory");
            }
            // Issue z loads for phase q first; emit_phase below hides their latency.
            vfloat4 zl[PH], zh[PH];
            #pragma unroll
            for (int s = 0; s < PH; ++s) {
                const float* g = zb + (size_t)(q * PH + s) * H_;
                zl[s] = *(const vfloat4*)g;
                zh[s] = *(const vfloat4*)(g + 4);
            }
            if (q >= 2) emit_phase(q - 2);
            const int half = q & 1;
            #pragma unroll
            for (int s = 0; s < PH; ++s) {
                const int t = q * PH + s;
                float x0 = xb[3*t], x1 = xb[3*t+1], x2 = xb[3*t+2];
                float zz[8] = {zl[s].x, zl[s].y, zl[s].z, zl[s].w,
                               zh[s].x, zh[s].y, zh[s].z, zh[s].w};
                float u[8];
                #pragma unroll
                for (int k = 0; k < 8; ++k) {
                    float xw = __builtin_fmaf(x0, wS0[k],
                               __builtin_fmaf(x1, wS1[k], x2 * wS2[k]));
                    u[k] = __builtin_fmaf(zz[k], 0.05f, xw);
                }
                vfloat4 ulo = {u[0], u[1], u[2], u[3]};
                vfloat4 uhi = {u[4], u[5], u[6], u[7]};
                ub[half][s][0][lane] = ulo;
                ub[half][s][1][lane] = uhi;
            }
            asm volatile("s_waitcnt lgkmcnt(0)" ::: "memory");
            if (lane == 0) *vprod = q + 1;   // also certifies os/traj(q-2) done
        }
        // Tail: phases 123, 124, then the final step's r and h_T.
        while (*vcons < NPHASE) {}            // consumer finished phase 124
        asm volatile("" ::: "memory");
        emit_phase(NPHASE - 2);
        emit_phase(NPHASE - 1);
        while (*vcons < NPHASE + 1) {}        // final r, h_T available
        asm volatile("" ::: "memory");
        {
            vfloat4 rl = rfin[0][lane], rh = rfin[1][lane];
            float p2 = rl.x * wof[0];
            p2 = __builtin_fmaf(rl.y, wof[1], p2);
            p2 = __builtin_fmaf(rl.z, wof[2], p2);
            p2 = __builtin_fmaf(rl.w, wof[3], p2);
            p2 = __builtin_fmaf(rh.x, wof[4], p2);
            p2 = __builtin_fmaf(rh.y, wof[5], p2);
            p2 = __builtin_fmaf(rh.z, wof[6], p2);
            p2 = __builtin_fmaf(rh.w, wof[7], p2);
            p2 = wave_reduce1(p2);
            if (lane == 63) os[T_] = p2;
            // trajectory row T = h_T
            float* tr = trajBase + (size_t)T_ * H_ + j0;
            *(vfloat4*)tr       = hfin[0][lane];
            *(vfloat4*)(tr + 4) = hfin[1][lane];
        }
        asm volatile("s_waitcnt lgkmcnt(0)" ::: "memory");
        float* outp = out + (size_t)b * T_;
        for (int idx = lane; idx < T_; idx += 64)
            outp[idx] = os[idx + 1];
    } else {
        // ========== CONSUMER: Taylor-in-delta chain (tanh off the critical path) ==========
        // State entering step t (parity pp = t&1):
        //   a0s,a1s   = a_{t-1}                       (a_{-1} = 0)
        //   bP[pp]    = base_{t-1}                    (base_{-1} = h_0)
        //   Tc[pp]    = tanh(base_{t-1}), Dc[pp] = 1 - Tc^2
        // Step t:  delta = a0*m~0 + a1*m~1  (|delta| ~ 0.01)
        //          h_t   = base_{t-1} + delta                       (exact)
        //          r_t   = Tc + Dc * delta*(1 - Tc*delta)           (2nd-order Taylor)
        //          base_t = 0.8 h_t + u_t ; T,D(base_t) via exp/rcp (OFF-chain)
        vfloat2 n02[4], n12[4], m02[4], m12[4];
        vfloat2 bP[2][4], Tc[2][4], Dc[2][4];
        {
            const float* nb = n + 2 * j0;
            const float* mb = m + 2 * j0;
            #pragma unroll
            for (int q = 0; q < 4; ++q) {
                vfloat4 vn = *(const vfloat4*)(nb + 4 * q);
                vfloat2 a = {vn.x, vn.z}; n02[q] = a;
                vfloat2 c = {vn.y, vn.w}; n12[q] = c;
                vfloat4 vm = *(const vfloat4*)(mb + 4 * q);
                vfloat2 d = {0.2f * vm.x, 0.2f * vm.z}; m02[q] = d;
                vfloat2 e = {0.2f * vm.y, 0.2f * vm.w}; m12[q] = e;
            }
            #pragma unroll
            for (int q = 0; q < 2; ++q) {
                vfloat4 vh = *(const vfloat4*)(h0 + j0 + 4 * q);
                vfloat2 lo = {vh.x, vh.y}, hi = {vh.z, vh.w};
                bP[0][2*q] = lo; bP[0][2*q+1] = hi;
            }
            #pragma unroll
            for (int j = 0; j < 4; ++j) {
                vfloat2 T = {fast_tanh(bP[0][j].x), fast_tanh(bP[0][j].y)};
                Tc[0][j] = T;
                Dc[0][j] = 1.0f - T * T;
            }
        }
        float a0s = 0.0f, a1s = 0.0f;

        for (int p = 0; p < NPHASE; ++p) {
            while (*vprod < p + 1) {}        // u ready AND ring slot p&1 free
            asm volatile("" ::: "memory");
            const int half = p & 1;
            vfloat4 cul = ub[half][0][0][lane];
            vfloat4 cuh = ub[half][0][1][lane];
            #pragma unroll
            for (int s = 0; s < PH; ++s) {
                const int pp = s & 1;        // compile-time after unroll
                const int np = pp ^ 1;
                vfloat4 nul, nuh;
                if (s < PH - 1) {            // prefetch next step's u
                    nul = ub[half][s+1][0][lane];
                    nuh = ub[half][s+1][1][lane];
                }
                vfloat2 a02 = bc2(a0s), a12 = bc2(a1s);

                // ---- ON-CHAIN: delta -> r -> dot -> reduce ----
                vfloat2 dl[4], r2[4], h2[4];
                #pragma unroll
                for (int j = 0; j < 4; ++j)
                    dl[j] = a02 * m02[j] + a12 * m12[j];         // delta (2 pk deep)
                #pragma unroll
                for (int j = 0; j < 4; ++j) {
                    vfloat2 t1 = Tc[pp][j] * dl[j];
                    vfloat2 e  = dl[j] - t1 * dl[j];             // delta*(1-T*delta)
                    r2[j] = Dc[pp][j] * e + Tc[pp][j];           // r (3 pk deep)
                }
                vfloat2 A0 = r2[1] * n02[1] + r2[0] * n02[0];
                vfloat2 B0 = r2[3] * n02[3] + r2[2] * n02[2];
                vfloat2 P0 = A0 + B0;
                float p0 = P0.x + P0.y;
                vfloat2 A1 = r2[1] * n12[1] + r2[0] * n12[0];
                vfloat2 B1 = r2[3] * n12[3] + r2[2] * n12[2];
                vfloat2 P1 = A1 + B1;
                float p1 = P1.x + P1.y;
                wave_reduce2(p0, p1);

                // ---- OFF-CHAIN (issues under the DPP window) ----
                vfloat2 u2[4];
                vfloat2 t0 = {cul.x, cul.y}; u2[0] = t0;
                vfloat2 t1v = {cul.z, cul.w}; u2[1] = t1v;
                vfloat2 t2 = {cuh.x, cuh.y}; u2[2] = t2;
                vfloat2 t3 = {cuh.z, cuh.w}; u2[3] = t3;
                #pragma unroll
                for (int j = 0; j < 4; ++j) {
                    h2[j] = bP[pp][j] + dl[j];                   // h_t exact
                    bP[np][j] = h2[j] * 0.8f + u2[j];            // base_t
                }
                #pragma unroll
                for (int j = 0; j < 4; ++j) {                    // T,D for step t+1
                    vfloat2 x2 = bP[np][j] * C2_;
                    vfloat2 E  = {__builtin_amdgcn_exp2f(x2.x),
                                  __builtin_amdgcn_exp2f(x2.y)};
                    vfloat2 DD = E + 1.0f;
                    vfloat2 R  = {__builtin_amdgcn_rcpf(DD.x),
                                  __builtin_amdgcn_rcpf(DD.y)};
                    vfloat2 T  = bc2(-2.0f) * R + 1.0f;
                    Tc[np][j] = T;
                    Dc[np][j] = 1.0f - T * T;
                }

                // Ship r_t (for os) and h_t (for traj row t) to the producer.
                vfloat4 rlo = {r2[0].x, r2[0].y, r2[1].x, r2[1].y};
                vfloat4 rhi = {r2[2].x, r2[2].y, r2[3].x, r2[3].y};
                rb[half][s][0][lane] = rlo;
                rb[half][s][1][lane] = rhi;
                vfloat4 hlo = {h2[0].x, h2[0].y, h2[1].x, h2[1].y};
                vfloat4 hhi = {h2[2].x, h2[2].y, h2[3].x, h2[3].y};
                hb[half][s][0][lane] = hlo;
                hb[half][s][1][lane] = hhi;

                // Broadcast the reduced sums for next step.
                a0s = __int_as_float(__builtin_amdgcn_readlane(__float_as_int(p0), 63));
                a1s = __int_as_float(__builtin_amdgcn_readlane(__float_as_int(p1), 63));

                cul = nul; cuh = nuh;
            }
            asm volatile("s_waitcnt lgkmcnt(0)" ::: "memory");  // rings visible
            if (lane == 0) *vcons = p + 1;
        }
        // Final step: h_T = base_999 + delta_999 (exact), r = tanh(h_T) for out[T-1].
        while (*vprod < NPHASE) {}           // producer done reading slot
        asm volatile("" ::: "memory");
        vfloat2 a02 = bc2(a0s), a12 = bc2(a1s);
        float r[8], hT8[8];
        #pragma unroll
        for (int j = 0; j < 4; ++j) {
            vfloat2 dlt = a02 * m02[j] + a12 * m12[j];
            vfloat2 hT  = bP[0][j] + dlt;                        // 1000 even -> parity 0
            hT8[2*j] = hT.x; hT8[2*j+1] = hT.y;
            r[2*j]   = fast_tanh(hT.x);
            r[2*j+1] = fast_tanh(hT.y);
        }
        vfloat4 rlo = {r[0], r[1], r[2], r[3]};
        vfloat4 rhi = {r[4], r[5], r[6], r[7]};
        rfin[0][lane] = rlo;
        rfin[1][lane] = rhi;
        vfloat4 hlo = {hT8[0], hT8[1], hT8[2], hT8[3]};
        vfloat4 hhi = {hT8[4], hT8[5], hT8[6], hT8[7]};
        hfin[0][lane] = hlo;
        hfin[1][lane] = hhi;
        asm volatile("s_waitcnt lgkmcnt(0)" ::: "memory");
        if (lane == 0) *vcons = NPHASE + 1;
    }
}

extern "C" void kernel_launch(void* const* d_in, const int* in_sizes, int n_in,
                              void* d_out, int out_size, void* d_ws, size_t ws_size,
                              hipStream_t stream) {
    const float* input = (const float*)d_in[0];
    const float* noise = (const float*)d_in[1];
    const float* wi    = (const float*)d_in[2];
    const float* si    = (const float*)d_in[3];
    const float* m     = (const float*)d_in[4];
    const float* n     = (const float*)d_in[5];
    const float* wo    = (const float*)d_in[6];
    const float* so    = (const float*)d_in[7];
    const float* h0    = (const float*)d_in[8];
    float* out = (float*)d_out;

    hipLaunchKernelGGL(lowrank_rnn_kernel, dim3(B_), dim3(128), 0, stream,
                       input, noise, wi, si, m, n, wo, so, h0, out);
}